// Round 15
// baseline (4124.496 us; speedup 1.0000x reference)
//
#include <hip/hip_runtime.h>
#include <math.h>

#define B_   2
#define N_   4096
#define V_   32768
#define K_   128
#define SC   16              // m-tiles of 256
#define CH   3
#define NEPS 12
#define XXB  512             // B * 16 n-chunks(256) * 16 m-tiles, 1 n/thread
#define FTB  48              // 6 bc * 8 n-chunks(512), 2 n/thread
#define GTB  192
#define YYB  6
#define NBLK (XXB + FTB + GTB + YYB)   // 758 <= 768 = 3 blocks/CU (launch_bounds 256,3)
#define TCAP 2048

#define LOG2E 1.4426950408889634f
#define LN2   0.6931471805599453f
#define EPS_LAST 0.0025f

typedef float f2 __attribute__((ext_vector_type(2)));

__constant__ float c_epsl[NEPS + 1] = {4.0f, 1.0f, 0.25f, 0.0625f, 0.015625f, 0.00390625f,
                                       0.0025f, 0.0025f, 0.0025f, 0.0025f, 0.0025f, 0.0025f,
                                       EPS_LAST};

// raw hardware transcendentals
__device__ __forceinline__ float fexp2(float x) {
  float r; asm("v_exp_f32 %0, %1" : "=v"(r) : "v"(x)); return r;
}
__device__ __forceinline__ float flog2(float x) {
  float r; asm("v_log_f32 %0, %1" : "=v"(r) : "v"(x)); return r;
}

// ---- static device scratch ----
__device__ float4 g_P   [B_*N_];
__device__ float  g_alog[B_*CH*N_];
__device__ float  g_fa  [2][B_*CH*N_];
__device__ float  g_partS[2][SC*CH*B_*N_];
__device__ float  g_Ubar[2][B_*SC*CH];
__device__ float4 g_pts [B_*CH*K_];
__device__ float  g_blog[B_*CH*K_];
__device__ float  g_bval[B_*CH*K_];
__device__ float  g_fbuf[2][B_*CH*N_];
__device__ float  g_gbuf[2][B_*CH*K_];
__device__ float  g_ybuf[2][B_*CH*K_];
__device__ float  g_S1a[FTB];
__device__ float  g_Gab[768];
__device__ float  g_S2[6];
__device__ float  g_S3[96];
// grid barrier (self-restoring; gen monotone, equality-tested)
__device__ unsigned g_bcnt;
__device__ unsigned g_bgen;

__device__ __forceinline__ void grid_bar() {
  __syncthreads();
  if (threadIdx.x == 0) {
    __threadfence();                                   // release my writes (device scope)
    unsigned gen = __hip_atomic_load(&g_bgen, __ATOMIC_ACQUIRE, __HIP_MEMORY_SCOPE_AGENT);
    unsigned prev = __hip_atomic_fetch_add(&g_bcnt, 1u, __ATOMIC_ACQ_REL, __HIP_MEMORY_SCOPE_AGENT);
    if (prev == NBLK - 1u) {
      __hip_atomic_store(&g_bcnt, 0u, __ATOMIC_RELAXED, __HIP_MEMORY_SCOPE_AGENT);
      __hip_atomic_store(&g_bgen, gen + 1u, __ATOMIC_RELEASE, __HIP_MEMORY_SCOPE_AGENT);
    } else {
      // device-scope atomic LOAD poll: coherent via LLC, parallel, no RMW serialization
      while (__hip_atomic_load(&g_bgen, __ATOMIC_ACQUIRE, __HIP_MEMORY_SCOPE_AGENT) == gen)
        __builtin_amdgcn_s_sleep(2);
    }
    __threadfence();
  }
  __syncthreads();
}

__device__ __forceinline__ void lse_up(float t, float& m, float& s) {
  float mn = fmaxf(m, t);
  float e  = fexp2(-fabsf(t - m));
  bool  gt = t > m;
  float mulv = gt ? e : 1.0f;
  float addv = gt ? 1.0f : e;
  s = fmaf(s, mulv, addv);
  m = mn;
}
__device__ __forceinline__ void lse_merge(float& M, float& S, float oM, float oS) {
  float mn = fmaxf(M, oM);
  float e  = fexp2(-fabsf(M - oM));
  bool  gt = oM > M;
  float sm = gt ? e : 1.0f;
  float so = gt ? 1.0f : e;
  S = fmaf(S, sm, oS * so);
  M = mn;
}

// ============ prep ============
__global__ __launch_bounds__(1024) void k_prep(const float* __restrict__ y) {
  const int bn = blockIdx.x * 1024 + threadIdx.x;
  const int b = bn >> 12, n = bn & (N_ - 1);
  const float* yr = y + (size_t)bn * 6;
  float x0 = yr[0], x1 = yr[1], x2 = yr[2];
  g_P[bn] = make_float4(x0, x1, x2, 0.5f * (x0*x0 + x1*x1 + x2*x2));
#pragma unroll
  for (int c = 0; c < CH; ++c) {
    float w  = yr[3 + c];
    float al = flog2(fmaxf(w, 1e-20f)) * LN2;
    const int o = (b*CH + c)*N_ + n;
    g_alog[o] = al; g_fa[0][o] = 0.f; g_fbuf[0][o] = 0.f;
  }
}

// ============ fused top-k: one block per (b,c) row, LDS histogram select ============
__global__ __launch_bounds__(1024) void k_topk(const float* __restrict__ yhat,
                                               const float* __restrict__ vox) {
  const int bc = blockIdx.x, tid = threadIdx.x;
  __shared__ int   s_hist[8192];
  __shared__ int   s_suf[1024];
  __shared__ float s_tv[TCAP];
  __shared__ int   s_ti[TCAP];
  __shared__ float s_wv[K_];
  __shared__ int   s_wi[K_];
  __shared__ int   s_wtot[16];
  __shared__ int   s_pos, s_eq, s_bs, s_c1, s_cnt;

  if (tid < K_) { g_gbuf[0][bc*K_ + tid] = 0.f; g_ybuf[0][bc*K_ + tid] = 0.f; }
#pragma unroll
  for (int j = 0; j < 8; ++j) s_hist[tid + j*1024] = 0;
  if (tid == 0) { s_pos = 0; s_eq = 0; }

  const float* row = yhat + (size_t)bc * V_;
  float v[32];
#pragma unroll
  for (int j = 0; j < 32; ++j) v[j] = row[tid + j * 1024];
  __syncthreads();
#pragma unroll
  for (int j = 0; j < 32; ++j) {
    unsigned b = __float_as_uint(v[j]);
    unsigned bk = (b >> 31) ? 0u : min(b >> 17, 8191u);
    atomicAdd(&s_hist[bk], 1);
  }
  __syncthreads();
  const int base = tid * 8;
  int cs = 0;
#pragma unroll
  for (int i = 0; i < 8; ++i) cs += s_hist[base + i];
  s_suf[tid] = cs;
  __syncthreads();
  for (int off = 1; off < 1024; off <<= 1) {
    int vv = s_suf[tid];
    int add = (tid + off < 1024) ? s_suf[tid + off] : 0;
    __syncthreads();
    s_suf[tid] = vv + add;
    __syncthreads();
  }
  int nxt = (tid < 1023) ? s_suf[tid + 1] : 0;
  if (s_suf[tid] >= K_ && nxt < K_) {
    int cnt = nxt, bstar = base, c1 = nxt;
    for (int b2 = base + 7; b2 >= base; --b2) {
      int h = s_hist[b2];
      if (cnt + h >= K_) { bstar = b2; c1 = cnt; break; }
      cnt += h;
    }
    s_bs = bstar; s_c1 = c1;
  }
  __syncthreads();
  const int bstar = s_bs, c1 = s_c1;
#pragma unroll
  for (int j = 0; j < 32; ++j) {
    unsigned b = __float_as_uint(v[j]);
    int bk = (b >> 31) ? 0 : (int)min(b >> 17, 8191u);
    int i = tid + j * 1024;
    if (bk > bstar) {
      int p = atomicAdd(&s_pos, 1);
      s_wv[p] = v[j]; s_wi[p] = i;
    } else if (bk == bstar) {
      int p = atomicAdd(&s_eq, 1);
      if (p < TCAP) { s_tv[p] = v[j]; s_ti[p] = i; }
    }
  }
  __syncthreads();
  const int tcnt = s_eq;
  if (tcnt <= TCAP) {
    const int need = K_ - c1;
    for (int e = tid; e < tcnt; e += 1024) {
      float vv = s_tv[e]; int i = s_ti[e];
      int rank = 0;
      for (int j2 = 0; j2 < tcnt; ++j2) {
        float ov = s_tv[j2]; int oi = s_ti[j2];
        rank += (ov > vv || (ov == vv && oi < i)) ? 1 : 0;
      }
      if (rank < need) { s_wv[c1 + rank] = vv; s_wi[c1 + rank] = i; }
    }
    __syncthreads();
  } else {
    unsigned lo = 0u, hi = 0x7f800000u;
    while (lo < hi) {
      unsigned mid = lo + ((hi - lo + 1u) >> 1);
      if (tid == 0) s_cnt = 0;
      __syncthreads();
      int local = 0;
#pragma unroll
      for (int j = 0; j < 32; ++j) local += (__float_as_uint(v[j]) >= mid) ? 1 : 0;
      for (int off = 32; off; off >>= 1) local += __shfl_down(local, off);
      if ((tid & 63) == 0 && local) atomicAdd(&s_cnt, local);
      __syncthreads();
      int cnt = s_cnt;
      __syncthreads();
      if (cnt >= K_) lo = mid; else hi = mid - 1u;
    }
    const unsigned T = lo;
    if (tid == 0) s_cnt = 0;
    __syncthreads();
#pragma unroll
    for (int j = 0; j < 32; ++j) {
      if (__float_as_uint(v[j]) > T) {
        int p = atomicAdd(&s_cnt, 1);
        s_wv[p] = v[j]; s_wi[p] = tid + j * 1024;
      }
    }
    __syncthreads();
    int got = s_cnt;
    __syncthreads();
    for (int chunk = 0; chunk < 32 && got < K_; ++chunk) {
      int i = chunk * 1024 + tid;
      bool f = (__float_as_uint(v[chunk]) == T);
      unsigned long long mask = __ballot(f);
      int lane = tid & 63, wv = tid >> 6;
      int wpre = __popcll(mask & ((1ULL << lane) - 1ULL));
      if (lane == 0) s_wtot[wv] = __popcll(mask);
      __syncthreads();
      int pre = wpre, tot = 0;
      for (int w = 0; w < 16; ++w) { if (w < wv) pre += s_wtot[w]; tot += s_wtot[w]; }
      if (f && got + pre < K_) { s_wv[got + pre] = v[chunk]; s_wi[got + pre] = i; }
      got = min(got + tot, K_);
      __syncthreads();
    }
  }
  if (tid < K_) {
    float mv = s_wv[tid]; int mi = s_wi[tid];
    float p0 = vox[(size_t)mi*3+0], p1 = vox[(size_t)mi*3+1], p2 = vox[(size_t)mi*3+2];
    g_pts [bc*K_ + tid] = make_float4(p0, p1, p2, 0.5f*(p0*p0 + p1*p1 + p2*p2));
    g_bval[bc*K_ + tid] = mv;
    g_blog[bc*K_ + tid] = flog2(fmaxf(mv, 1e-20f)) * LN2;
  }
}

// ============ persistent: 13 fused passes + finalize + total ============
__global__ __launch_bounds__(256, 3) void k_all(const float* __restrict__ y,
                                                float* __restrict__ out) {
  const int blk = blockIdx.x, tid = threadIdx.x;
  __shared__ float s_M[2048];     // 128 records x 16 floats (xx) / aliased by ft,yy
  __shared__ float s_scale[48];
  __shared__ float s_Mx[3];
  __shared__ float s_w[12];

  for (int it = 0; it <= NEPS; ++it) {
    const float eps = c_epsl[it];
    const float eps_prev = (it > 0) ? c_epsl[it - 1] : 1.0f;
    const int mode = (it == NEPS) ? 1 : 0;
    const float il = LOG2E / eps, nil = -il;
    const int src = it & 1;

    if (blk < XXB) {
      // ---- xx block (b, I, J): inline combine for m-tile J, then 256n x 256m (1 n/thread) ----
      const int J = blk & 15;
      const int I = (blk >> 4) & 15;
      const int b = blk >> 8;
      const int r  = (J << 8) + tid;
      const int bn_r = b*N_ + r;
      float U[CH];
      if (it == 0) {
#pragma unroll
        for (int c = 0; c < CH; ++c) U[c] = LOG2E * g_alog[(b*CH + c)*N_ + r];
      } else {
        const int pv = src ^ 1;
        if (tid < 48) {
          int c = tid >> 4, Jp = tid & 15;
          s_scale[tid] = g_Ubar[pv][(b*SC + Jp)*CH + c];
        }
        __syncthreads();
        if (tid < 3) {
          float mm = s_scale[tid*16];
#pragma unroll
          for (int j = 1; j < 16; ++j) mm = fmaxf(mm, s_scale[tid*16 + j]);
          s_Mx[tid] = mm;
        }
        __syncthreads();
        if (tid < 48) s_scale[tid] = fexp2(s_scale[tid] - s_Mx[tid >> 4]);
        __syncthreads();
#pragma unroll
        for (int c = 0; c < CH; ++c) {
          float S = 0.f;
#pragma unroll
          for (int Jp = 0; Jp < 16; ++Jp)
            S = fmaf(g_partS[pv][(Jp*CH + c)*(B_*N_) + bn_r], s_scale[c*16 + Jp], S);
          float sm = -eps_prev * LN2 * (s_Mx[c] + flog2(S));
          const int o = (b*CH + c)*N_ + r;
          float fn = 0.5f * (g_fa[src ^ 1][o] + sm);
          g_fa[src][o] = fn;
          U[c] = fmaf(fn, il, LOG2E * g_alog[o]);
        }
        __syncthreads();
      }
      float Ub[CH];
#pragma unroll
      for (int c = 0; c < CH; ++c) {
        float u = U[c];
        for (int off = 32; off; off >>= 1) u = fmaxf(u, __shfl_xor(u, off));
        if ((tid & 63) == 0) s_w[(tid >> 6)*3 + c] = u;
      }
      __syncthreads();
#pragma unroll
      for (int c = 0; c < CH; ++c)
        Ub[c] = fmaxf(fmaxf(s_w[c], s_w[3 + c]), fmaxf(s_w[6 + c], s_w[9 + c]));
      if (tid < 3) g_Ubar[src][(b*SC + J)*CH + tid] = Ub[tid];
      {
        float4 Pm = g_P[bn_r];
        const int pp = tid >> 1, par = tid & 1;
        float* rec = s_M + pp*16;
        rec[0 + par] = il * Pm.x;
        rec[2 + par] = il * Pm.y;
        rec[4 + par] = il * Pm.z;
        rec[6 + par] = -il * Pm.w;
#pragma unroll
        for (int c = 0; c < CH; ++c) rec[8 + 2*c + par] = fexp2(U[c] - Ub[c]);
      }
      __syncthreads();
      const int bn0 = b*N_ + (I << 8) + tid;
      const float4 Pn0 = g_P[bn0];
      const float xs0 = Pn0.x, ys0 = Pn0.y, zs0 = Pn0.z, nn0 = nil * Pn0.w;
      const f2 zz = {0.f, 0.f};
      f2 a00 = zz, a01 = zz, a02 = zz;
#pragma unroll 4
      for (int j = 0; j < 128; ++j) {
        const float* Mj = s_M + j*16;
        const float4 q0 = *(const float4*)(Mj);
        const float4 q1 = *(const float4*)(Mj + 4);
        const float4 q2 = *(const float4*)(Mj + 8);
        const float2 q3 = *(const float2*)(Mj + 12);
        f2 t0 = f2{q1.z, q1.w} + nn0;
        t0 = f2{q1.x, q1.y} * zs0 + t0;
        t0 = f2{q0.z, q0.w} * ys0 + t0;
        t0 = f2{q0.x, q0.y} * xs0 + t0;
        t0 = __builtin_elementwise_min(t0, zz);
        f2 e0; e0.x = fexp2(t0.x); e0.y = fexp2(t0.y);
        a00 = f2{q2.x, q2.y} * e0 + a00;
        a01 = f2{q2.z, q2.w} * e0 + a01;
        a02 = f2{q3.x, q3.y} * e0 + a02;
      }
      float* pc = g_partS[src];
      pc[(J*CH + 0)*(B_*N_) + bn0] = a00.x + a00.y;
      pc[(J*CH + 1)*(B_*N_) + bn0] = a01.x + a01.y;
      pc[(J*CH + 2)*(B_*N_) + bn0] = a02.x + a02.y;
    } else if (blk < XXB + FTB) {
      // ---- ab ft: 2 n per thread ----
      float4* s_A = (float4*)s_M;
      float*  s_C = s_M + 512;
      float*  s_D = s_M + 640;
      const int blk2 = blk - XXB;           // [0,48)
      const int bc = blk2 >> 3;
      const int b = bc / 3, c = bc % 3;
      const int n0 = ((blk2 & 7) << 9) + tid;
      const int n1 = n0 + 256;
      float Hk = -INFINITY;
      if (tid < K_) {
        float g = g_gbuf[src][bc*K_ + tid];
        Hk = fmaf(g, il, LOG2E * g_blog[bc*K_ + tid]);
        s_A[tid] = g_pts[bc*K_ + tid];
      }
      float hm = Hk;
      for (int off = 32; off; off >>= 1) hm = fmaxf(hm, __shfl_xor(hm, off));
      if ((tid & 63) == 0) s_w[tid >> 6] = hm;
      __syncthreads();
      const float Hbar = fmaxf(fmaxf(s_w[0], s_w[1]), fmaxf(s_w[2], s_w[3]));
      if (tid < K_) { float dh = Hk - Hbar; s_C[tid] = fexp2(dh); s_D[tid] = dh; }
      float4 Pn0 = g_P[b*N_ + n0], Pn1 = g_P[b*N_ + n1];
      __syncthreads();
      float S0 = 0.f, M0 = -INFINITY, S1 = 0.f, M1 = -INFINITY;
#pragma unroll 2
      for (int k2 = 0; k2 < K_; ++k2) {
        float4 p1 = s_A[k2];
        float ec = s_C[k2], dh = s_D[k2];
        float d0 = fmaf(Pn0.x, p1.x, fmaf(Pn0.y, p1.y, Pn0.z * p1.z));
        float C0 = fmaxf((Pn0.w + p1.w) - d0, 0.f);
        float w0 = C0 * nil;
        S0 = fmaf(ec, fexp2(w0), S0);
        M0 = fmaxf(M0, w0 + dh);
        float d1 = fmaf(Pn1.x, p1.x, fmaf(Pn1.y, p1.y, Pn1.z * p1.z));
        float C1 = fmaxf((Pn1.w + p1.w) - d1, 0.f);
        float w1 = C1 * nil;
        S1 = fmaf(ec, fexp2(w1), S1);
        M1 = fmaxf(M1, w1 + dh);
      }
      float lse0 = (S0 > 0.f) ? flog2(S0) : M0;
      float lse1 = (S1 > 0.f) ? flog2(S1) : M1;
      float ft0 = -eps * LN2 * (Hbar + lse0);
      float ft1 = -eps * LN2 * (Hbar + lse1);
      if (mode == 0) {
        g_fbuf[src ^ 1][bc*N_ + n0] = 0.5f * (g_fbuf[src][bc*N_ + n0] + ft0);
        g_fbuf[src ^ 1][bc*N_ + n1] = 0.5f * (g_fbuf[src][bc*N_ + n1] + ft1);
      } else {
        float a0 = y[(size_t)(b*N_ + n0) * 6 + 3 + c];
        float a1 = y[(size_t)(b*N_ + n1) * 6 + 3 + c];
        float acc = a0 * ft0 + a1 * ft1;
        for (int off = 32; off; off >>= 1) acc += __shfl_down(acc, off);
        __syncthreads();
        if ((tid & 63) == 0) s_w[tid >> 6] = acc;
        __syncthreads();
        if (tid == 0) g_S1a[blk2] = s_w[0] + s_w[1] + s_w[2] + s_w[3];
      }
      __syncthreads();
    } else if (blk < XXB + FTB + GTB) {
      // ---- ab gt: one wave per (bc,k), 4 LSE chains ----
      const int job = (blk - (XXB + FTB)) * 4 + (tid >> 6);
      const int bc = job >> 7, k = job & (K_ - 1);
      const int b = bc / 3;
      const int lane = tid & 63;
      float4 Pk = g_pts[bc*K_ + k];
      float M0=-INFINITY,S0=0.f,M1=-INFINITY,S1=0.f,M2=-INFINITY,S2=0.f,M3=-INFINITY,S3=0.f;
      for (int j = 0; j < 64; j += 4) {
#pragma unroll
        for (int u = 0; u < 4; ++u) {
          int n = ((j + u) << 6) + lane;
          float4 pm = g_P[b*N_ + n];
          float Hn = fmaf(g_fbuf[src][bc*N_ + n], il, LOG2E * g_alog[bc*N_ + n]);
          float d = fmaf(Pk.x, pm.x, fmaf(Pk.y, pm.y, Pk.z * pm.z));
          float C = fmaxf((Pk.w + pm.w) - d, 0.f);
          float t = fmaf(C, nil, Hn);
          if (u == 0) lse_up(t, M0, S0);
          else if (u == 1) lse_up(t, M1, S1);
          else if (u == 2) lse_up(t, M2, S2);
          else lse_up(t, M3, S3);
        }
      }
      lse_merge(M0, S0, M1, S1);
      lse_merge(M2, S2, M3, S3);
      lse_merge(M0, S0, M2, S2);
      for (int off = 1; off < 64; off <<= 1) {
        float oM = __shfl_xor(M0, off);
        float oS = __shfl_xor(S0, off);
        lse_merge(M0, S0, oM, oS);
      }
      if (lane == 0) {
        float gt = -eps * LN2 * (M0 + flog2(S0));
        const int o = bc*K_ + k;
        if (mode == 0) g_gbuf[src ^ 1][o] = 0.5f * (g_gbuf[src][o] + gt);
        else           g_Gab[job] = g_bval[o] * gt;
      }
    } else {
      // ---- yy ----
      float4* s_A = (float4*)s_M;
      float*  s_C = s_M + 512;
      float*  s_D = s_M + 640;
      const int bc = blk - (XXB + FTB + GTB);
      const int k = tid & (K_ - 1);
      if (tid < K_) {
        s_A[tid] = g_pts[bc*K_ + tid];
        float g = g_ybuf[src][bc*K_ + tid];
        s_C[tid] = fmaf(g, il, LOG2E * g_blog[bc*K_ + tid]);
        s_D[tid] = g;
      }
      __syncthreads();
      float4 Pk = s_A[k];
      float M = -INFINITY, S = 0.f;
      for (int m = 0; m < K_; ++m) {
        float4 pm = s_A[m];
        float d = fmaf(Pk.x, pm.x, fmaf(Pk.y, pm.y, Pk.z * pm.z));
        float C = fmaxf((Pk.w + pm.w) - d, 0.f);
        lse_up(fmaf(C, nil, s_C[m]), M, S);
      }
      float sv = -eps * LN2 * (M + flog2(S));
      if (mode == 0) {
        if (tid < K_) g_ybuf[src ^ 1][bc*K_ + k] = 0.5f * (s_D[k] + sv);
        __syncthreads();
      } else {
        float val = (tid < K_) ? g_bval[bc*K_ + k] * sv : 0.f;
        for (int off = 32; off; off >>= 1) val += __shfl_down(val, off);
        __syncthreads();
        if ((tid & 63) == 0) s_w[tid >> 6] = val;
        __syncthreads();
        if (tid == 0) g_S2[bc] = s_w[0] + s_w[1] + s_w[2] + s_w[3];
      }
    }
    grid_bar();
  }

  // ---- finalize: F_a combine + a*F_a partial sums (blocks 0..95) ----
  if (blk < 96) {
    const int idx = blk * 256 + tid;
    const int c  = idx >> 13;
    const int bn = idx & (B_*N_ - 1);
    const int b = bn >> 12, n = bn & (N_ - 1);
    if (tid < SC) s_scale[tid] = g_Ubar[0][(b*SC + tid)*CH + c];
    __syncthreads();
    if (tid == 0) {
      float mm = s_scale[0];
#pragma unroll
      for (int s = 1; s < SC; ++s) mm = fmaxf(mm, s_scale[s]);
      s_Mx[0] = mm;
    }
    __syncthreads();
    const float Mmax = s_Mx[0];
    if (tid < SC) s_scale[tid] = fexp2(s_scale[tid] - Mmax);
    __syncthreads();
    float S = 0.f;
#pragma unroll
    for (int s = 0; s < SC; ++s)
      S = fmaf(g_partS[0][(s*CH + c)*(B_*N_) + bn], s_scale[s], S);
    float sm = -EPS_LAST * LN2 * (Mmax + flog2(S));   // F_a
    float a = y[(size_t)(b*N_ + n)*6 + 3 + c];
    float acc = a * sm;
    for (int off = 32; off; off >>= 1) acc += __shfl_down(acc, off);
    if ((tid & 63) == 0) s_w[tid >> 6] = acc;
    __syncthreads();
    if (tid == 0) g_S3[blk] = s_w[0] + s_w[1] + s_w[2] + s_w[3];
  }
  grid_bar();

  // ---- total (block 0) ----
  if (blk == 0) {
    float local = 0.f;
    for (int i = tid; i < 768; i += 256) local += g_Gab[i];
    if (tid < FTB) local += g_S1a[tid];
    if (tid < 96)  local -= g_S3[tid];
    if (tid < 6)   local -= g_S2[tid];
    for (int off = 32; off; off >>= 1) local += __shfl_down(local, off);
    if ((tid & 63) == 0) s_w[tid >> 6] = local;
    __syncthreads();
    if (tid == 0) out[0] = s_w[0] + s_w[1] + s_w[2] + s_w[3];
  }
}

extern "C" void kernel_launch(void* const* d_in, const int* in_sizes, int n_in,
                              void* d_out, int out_size, void* d_ws, size_t ws_size,
                              hipStream_t stream) {
  const float* y_hat = (const float*)d_in[0];
  const float* y     = (const float*)d_in[1];
  const float* vox   = (const float*)d_in[2];
  float* out = (float*)d_out;

  k_prep<<<8, 1024, 0, stream>>>(y);
  k_topk<<<6, 1024, 0, stream>>>(y_hat, vox);
  k_all<<<NBLK, 256, 0, stream>>>(y, out);
}

// Round 16
// 281.928 us; speedup vs baseline: 14.6296x; 14.6296x over previous
//
#include <hip/hip_runtime.h>
#include <math.h>

#define B_   2
#define N_   4096
#define V_   32768
#define K_   128
#define SC   16              // m-tiles of 256
#define CH   3
#define NEPS 12
#define XXB  256             // B * 8 n-chunks(512) * 16 m-tiles, 2 n/thread
#define FTB  96
#define GTB  192
#define YYB  6
#define PRE  (GTB + FTB + YYB)         // small branches first: 294
#define NBLK (PRE + XXB)               // 550
#define TCAP 2048

#define LOG2E 1.4426950408889634f
#define LN2   0.6931471805599453f
#define EPS_LAST 0.0025f

typedef float f2 __attribute__((ext_vector_type(2)));

// raw hardware transcendentals (skip OCML subnormal-fixup wrappers)
__device__ __forceinline__ float fexp2(float x) {
  float r; asm("v_exp_f32 %0, %1" : "=v"(r) : "v"(x)); return r;
}
__device__ __forceinline__ float flog2(float x) {
  float r; asm("v_log_f32 %0, %1" : "=v"(r) : "v"(x)); return r;
}

// ---- static device scratch (ping-pong where cross-pass) ----
__device__ float4 g_P   [B_*N_];
__device__ float  g_alog[B_*CH*N_];
__device__ float  g_fa  [2][B_*CH*N_];
__device__ float  g_partS[2][SC*CH*B_*N_];
__device__ float  g_Ubar[2][B_*SC*CH];
__device__ float4 g_pts [B_*CH*K_];
__device__ float  g_blog[B_*CH*K_];
__device__ float  g_bval[B_*CH*K_];
__device__ float  g_fbuf[2][B_*CH*N_];
__device__ float  g_gbuf[2][B_*CH*K_];
__device__ float  g_ybuf[2][B_*CH*K_];
__device__ float  g_S1a[FTB];
__device__ float  g_Gab[768];
__device__ float  g_S2[6];
__device__ float  g_S3[96];

__device__ __forceinline__ void lse_up(float t, float& m, float& s) {
  float mn = fmaxf(m, t);
  float e  = fexp2(-fabsf(t - m));
  bool  gt = t > m;
  float mulv = gt ? e : 1.0f;
  float addv = gt ? 1.0f : e;
  s = fmaf(s, mulv, addv);
  m = mn;
}
__device__ __forceinline__ void lse_merge(float& M, float& S, float oM, float oS) {
  float mn = fmaxf(M, oM);
  float e  = fexp2(-fabsf(M - oM));
  bool  gt = oM > M;
  float sm = gt ? e : 1.0f;
  float so = gt ? 1.0f : e;
  S = fmaf(S, sm, oS * so);
  M = mn;
}

// ============ prep ============
__global__ __launch_bounds__(1024) void k_prep(const float* __restrict__ y) {
  const int bn = blockIdx.x * 1024 + threadIdx.x;
  const int b = bn >> 12, n = bn & (N_ - 1);
  const float* yr = y + (size_t)bn * 6;
  float x0 = yr[0], x1 = yr[1], x2 = yr[2];
  g_P[bn] = make_float4(x0, x1, x2, 0.5f * (x0*x0 + x1*x1 + x2*x2));
#pragma unroll
  for (int c = 0; c < CH; ++c) {
    float w  = yr[3 + c];
    float al = flog2(fmaxf(w, 1e-20f)) * LN2;
    const int o = (b*CH + c)*N_ + n;
    g_alog[o] = al; g_fa[0][o] = 0.f; g_fbuf[0][o] = 0.f;
  }
}

// ============ fused top-k: one block per (b,c) row, LDS histogram select ============
__global__ __launch_bounds__(1024) void k_topk(const float* __restrict__ yhat,
                                               const float* __restrict__ vox) {
  const int bc = blockIdx.x, tid = threadIdx.x;
  __shared__ int   s_hist[8192];
  __shared__ int   s_suf[1024];
  __shared__ float s_tv[TCAP];
  __shared__ int   s_ti[TCAP];
  __shared__ float s_wv[K_];
  __shared__ int   s_wi[K_];
  __shared__ int   s_wtot[16];
  __shared__ int   s_pos, s_eq, s_bs, s_c1, s_cnt;

  if (tid < K_) { g_gbuf[0][bc*K_ + tid] = 0.f; g_ybuf[0][bc*K_ + tid] = 0.f; }
#pragma unroll
  for (int j = 0; j < 8; ++j) s_hist[tid + j*1024] = 0;
  if (tid == 0) { s_pos = 0; s_eq = 0; }

  const float* row = yhat + (size_t)bc * V_;
  float v[32];
#pragma unroll
  for (int j = 0; j < 32; ++j) v[j] = row[tid + j * 1024];
  __syncthreads();
#pragma unroll
  for (int j = 0; j < 32; ++j) {
    unsigned b = __float_as_uint(v[j]);
    unsigned bk = (b >> 31) ? 0u : min(b >> 17, 8191u);
    atomicAdd(&s_hist[bk], 1);
  }
  __syncthreads();
  const int base = tid * 8;
  int cs = 0;
#pragma unroll
  for (int i = 0; i < 8; ++i) cs += s_hist[base + i];
  s_suf[tid] = cs;
  __syncthreads();
  for (int off = 1; off < 1024; off <<= 1) {
    int vv = s_suf[tid];
    int add = (tid + off < 1024) ? s_suf[tid + off] : 0;
    __syncthreads();
    s_suf[tid] = vv + add;
    __syncthreads();
  }
  int nxt = (tid < 1023) ? s_suf[tid + 1] : 0;
  if (s_suf[tid] >= K_ && nxt < K_) {
    int cnt = nxt, bstar = base, c1 = nxt;
    for (int b2 = base + 7; b2 >= base; --b2) {
      int h = s_hist[b2];
      if (cnt + h >= K_) { bstar = b2; c1 = cnt; break; }
      cnt += h;
    }
    s_bs = bstar; s_c1 = c1;
  }
  __syncthreads();
  const int bstar = s_bs, c1 = s_c1;
#pragma unroll
  for (int j = 0; j < 32; ++j) {
    unsigned b = __float_as_uint(v[j]);
    int bk = (b >> 31) ? 0 : (int)min(b >> 17, 8191u);
    int i = tid + j * 1024;
    if (bk > bstar) {
      int p = atomicAdd(&s_pos, 1);
      s_wv[p] = v[j]; s_wi[p] = i;
    } else if (bk == bstar) {
      int p = atomicAdd(&s_eq, 1);
      if (p < TCAP) { s_tv[p] = v[j]; s_ti[p] = i; }
    }
  }
  __syncthreads();
  const int tcnt = s_eq;
  if (tcnt <= TCAP) {
    const int need = K_ - c1;
    for (int e = tid; e < tcnt; e += 1024) {
      float vv = s_tv[e]; int i = s_ti[e];
      int rank = 0;
      for (int j2 = 0; j2 < tcnt; ++j2) {
        float ov = s_tv[j2]; int oi = s_ti[j2];
        rank += (ov > vv || (ov == vv && oi < i)) ? 1 : 0;
      }
      if (rank < need) { s_wv[c1 + rank] = vv; s_wi[c1 + rank] = i; }
    }
    __syncthreads();
  } else {
    unsigned lo = 0u, hi = 0x7f800000u;
    while (lo < hi) {
      unsigned mid = lo + ((hi - lo + 1u) >> 1);
      if (tid == 0) s_cnt = 0;
      __syncthreads();
      int local = 0;
#pragma unroll
      for (int j = 0; j < 32; ++j) local += (__float_as_uint(v[j]) >= mid) ? 1 : 0;
      for (int off = 32; off; off >>= 1) local += __shfl_down(local, off);
      if ((tid & 63) == 0 && local) atomicAdd(&s_cnt, local);
      __syncthreads();
      int cnt = s_cnt;
      __syncthreads();
      if (cnt >= K_) lo = mid; else hi = mid - 1u;
    }
    const unsigned T = lo;
    if (tid == 0) s_cnt = 0;
    __syncthreads();
#pragma unroll
    for (int j = 0; j < 32; ++j) {
      if (__float_as_uint(v[j]) > T) {
        int p = atomicAdd(&s_cnt, 1);
        s_wv[p] = v[j]; s_wi[p] = tid + j * 1024;
      }
    }
    __syncthreads();
    int got = s_cnt;
    __syncthreads();
    for (int chunk = 0; chunk < 32 && got < K_; ++chunk) {
      int i = chunk * 1024 + tid;
      bool f = (__float_as_uint(v[chunk]) == T);
      unsigned long long mask = __ballot(f);
      int lane = tid & 63, wv = tid >> 6;
      int wpre = __popcll(mask & ((1ULL << lane) - 1ULL));
      if (lane == 0) s_wtot[wv] = __popcll(mask);
      __syncthreads();
      int pre = wpre, tot = 0;
      for (int w = 0; w < 16; ++w) { if (w < wv) pre += s_wtot[w]; tot += s_wtot[w]; }
      if (f && got + pre < K_) { s_wv[got + pre] = v[chunk]; s_wi[got + pre] = i; }
      got = min(got + tot, K_);
      __syncthreads();
    }
  }
  if (tid < K_) {
    float mv = s_wv[tid]; int mi = s_wi[tid];
    float p0 = vox[(size_t)mi*3+0], p1 = vox[(size_t)mi*3+1], p2 = vox[(size_t)mi*3+2];
    g_pts [bc*K_ + tid] = make_float4(p0, p1, p2, 0.5f*(p0*p0 + p1*p1 + p2*p2));
    g_bval[bc*K_ + tid] = mv;
    g_blog[bc*K_ + tid] = flog2(fmaxf(mv, 1e-20f)) * LN2;
  }
}

// ============ fused pass: gt(192) + ft(96) + yy(6) first, then xx(256) ============
__global__ __launch_bounds__(256) void k_pass(float eps, float eps_prev, int it, int mode,
                                              const float* __restrict__ y) {
  const float il = LOG2E / eps, nil = -il;
  const int blk = blockIdx.x, tid = threadIdx.x;
  const int src = it & 1;
  __shared__ float s_M[2048];     // 128 records x 16 floats (xx) / aliased by ft,yy
  __shared__ float s_scale[48];
  __shared__ float s_Mx[3];
  __shared__ float s_w[12];

  if (blk >= PRE) {
    // ---- xx block (b, I, J): inline combine for m-tile J, then 512n x 256m loop ----
    const int blk2 = blk - PRE;
    const int J = blk2 & 15;
    const int I = (blk2 >> 4) & 7;
    const int b = blk2 >> 7;
    const int r  = (J << 8) + tid;          // this thread's m-row
    const int bn_r = b*N_ + r;
    float U[CH];
    if (it == 0) {
#pragma unroll
      for (int c = 0; c < CH; ++c) U[c] = LOG2E * g_alog[(b*CH + c)*N_ + r];
    } else {
      const int pv = src ^ 1;
      if (tid < 48) {
        int c = tid >> 4, Jp = tid & 15;
        s_scale[tid] = g_Ubar[pv][(b*SC + Jp)*CH + c];
      }
      __syncthreads();
      if (tid < 3) {
        float mm = s_scale[tid*16];
#pragma unroll
        for (int j = 1; j < 16; ++j) mm = fmaxf(mm, s_scale[tid*16 + j]);
        s_Mx[tid] = mm;
      }
      __syncthreads();
      if (tid < 48) s_scale[tid] = fexp2(s_scale[tid] - s_Mx[tid >> 4]);
      __syncthreads();
#pragma unroll
      for (int c = 0; c < CH; ++c) {
        float S = 0.f;
#pragma unroll
        for (int Jp = 0; Jp < 16; ++Jp)
          S = fmaf(g_partS[pv][(Jp*CH + c)*(B_*N_) + bn_r], s_scale[c*16 + Jp], S);
        float sm = -eps_prev * LN2 * (s_Mx[c] + flog2(S));
        const int o = (b*CH + c)*N_ + r;
        float fn = 0.5f * (g_fa[src ^ 1][o] + sm);
        g_fa[src][o] = fn;
        U[c] = fmaf(fn, il, LOG2E * g_alog[o]);
      }
      __syncthreads();                       // s_scale/s_Mx done before reuse of LDS
    }
    // tile max of U per channel
    float Ub[CH];
#pragma unroll
    for (int c = 0; c < CH; ++c) {
      float u = U[c];
      for (int off = 32; off; off >>= 1) u = fmaxf(u, __shfl_xor(u, off));
      if ((tid & 63) == 0) s_w[(tid >> 6)*3 + c] = u;
    }
    __syncthreads();
#pragma unroll
    for (int c = 0; c < CH; ++c)
      Ub[c] = fmaxf(fmaxf(s_w[c], s_w[3 + c]), fmaxf(s_w[6 + c], s_w[9 + c]));
    if (tid < 3) g_Ubar[src][(b*SC + J)*CH + tid] = Ub[tid];
    // build prescaled record tile in LDS
    {
      float4 Pm = g_P[bn_r];
      const int pp = tid >> 1, par = tid & 1;
      float* rec = s_M + pp*16;
      rec[0 + par] = il * Pm.x;
      rec[2 + par] = il * Pm.y;
      rec[4 + par] = il * Pm.z;
      rec[6 + par] = -il * Pm.w;
#pragma unroll
      for (int c = 0; c < CH; ++c) rec[8 + 2*c + par] = fexp2(U[c] - Ub[c]);
    }
    __syncthreads();
    // n loop: 2 n per thread
    const int bn0 = b*N_ + (I << 9) + tid;
    const int bn1 = bn0 + 256;
    const float4 Pn0 = g_P[bn0], Pn1 = g_P[bn1];
    const float xs0 = Pn0.x, ys0 = Pn0.y, zs0 = Pn0.z, nn0 = nil * Pn0.w;
    const float xs1 = Pn1.x, ys1 = Pn1.y, zs1 = Pn1.z, nn1 = nil * Pn1.w;
    const f2 zz = {0.f, 0.f};
    f2 a00 = zz, a01 = zz, a02 = zz, a10 = zz, a11 = zz, a12 = zz;
    for (int j = 0; j < 128; ++j) {
      const float* Mj = s_M + j*16;
      const float4 q0 = *(const float4*)(Mj);
      const float4 q1 = *(const float4*)(Mj + 4);
      const float4 q2 = *(const float4*)(Mj + 8);
      const float2 q3 = *(const float2*)(Mj + 12);
      f2 t0 = f2{q1.z, q1.w} + nn0;
      t0 = f2{q1.x, q1.y} * zs0 + t0;
      t0 = f2{q0.z, q0.w} * ys0 + t0;
      t0 = f2{q0.x, q0.y} * xs0 + t0;
      t0 = __builtin_elementwise_min(t0, zz);
      f2 e0; e0.x = fexp2(t0.x); e0.y = fexp2(t0.y);
      a00 = f2{q2.x, q2.y} * e0 + a00;
      a01 = f2{q2.z, q2.w} * e0 + a01;
      a02 = f2{q3.x, q3.y} * e0 + a02;
      f2 t1 = f2{q1.z, q1.w} + nn1;
      t1 = f2{q1.x, q1.y} * zs1 + t1;
      t1 = f2{q0.z, q0.w} * ys1 + t1;
      t1 = f2{q0.x, q0.y} * xs1 + t1;
      t1 = __builtin_elementwise_min(t1, zz);
      f2 e1; e1.x = fexp2(t1.x); e1.y = fexp2(t1.y);
      a10 = f2{q2.x, q2.y} * e1 + a10;
      a11 = f2{q2.z, q2.w} * e1 + a11;
      a12 = f2{q3.x, q3.y} * e1 + a12;
    }
    float* pc = g_partS[src];
    pc[(J*CH + 0)*(B_*N_) + bn0] = a00.x + a00.y;
    pc[(J*CH + 1)*(B_*N_) + bn0] = a01.x + a01.y;
    pc[(J*CH + 2)*(B_*N_) + bn0] = a02.x + a02.y;
    pc[(J*CH + 0)*(B_*N_) + bn1] = a10.x + a10.y;
    pc[(J*CH + 1)*(B_*N_) + bn1] = a11.x + a11.y;
    pc[(J*CH + 2)*(B_*N_) + bn1] = a12.x + a12.y;
  } else if (blk < GTB) {
    // ---- ab gt: one wave per (bc,k), 4 LSE chains ----
    const int job = blk * 4 + (tid >> 6);
    const int bc = job >> 7, k = job & (K_ - 1);
    const int b = bc / 3;
    const int lane = tid & 63;
    float4 Pk = g_pts[bc*K_ + k];
    float M0=-INFINITY,S0=0.f,M1=-INFINITY,S1=0.f,M2=-INFINITY,S2=0.f,M3=-INFINITY,S3=0.f;
    for (int j = 0; j < 64; j += 4) {
#pragma unroll
      for (int u = 0; u < 4; ++u) {
        int n = ((j + u) << 6) + lane;
        float4 pm = g_P[b*N_ + n];
        float Hn = fmaf(g_fbuf[src][bc*N_ + n], il, LOG2E * g_alog[bc*N_ + n]);
        float d = fmaf(Pk.x, pm.x, fmaf(Pk.y, pm.y, Pk.z * pm.z));
        float C = fmaxf((Pk.w + pm.w) - d, 0.f);
        float t = fmaf(C, nil, Hn);
        if (u == 0) lse_up(t, M0, S0);
        else if (u == 1) lse_up(t, M1, S1);
        else if (u == 2) lse_up(t, M2, S2);
        else lse_up(t, M3, S3);
      }
    }
    lse_merge(M0, S0, M1, S1);
    lse_merge(M2, S2, M3, S3);
    lse_merge(M0, S0, M2, S2);
    for (int off = 1; off < 64; off <<= 1) {
      float oM = __shfl_xor(M0, off);
      float oS = __shfl_xor(S0, off);
      lse_merge(M0, S0, oM, oS);
    }
    if (lane == 0) {
      float gt = -eps * LN2 * (M0 + flog2(S0));
      const int o = bc*K_ + k;
      if (mode == 0) g_gbuf[src ^ 1][o] = 0.5f * (g_gbuf[src][o] + gt);
      else           g_Gab[job] = g_bval[o] * gt;
    }
  } else if (blk < GTB + FTB) {
    // ---- ab ft ----
    float4* s_A = (float4*)s_M;           // [128]
    float*  s_C = s_M + 512;
    float*  s_D = s_M + 640;
    const int blk2 = blk - GTB;
    const int bc = blk2 >> 4;
    const int b = bc / 3, c = bc % 3;
    const int n = ((blk2 & 15) << 8) + tid;
    float Hk = -INFINITY;
    if (tid < K_) {
      float g = g_gbuf[src][bc*K_ + tid];
      Hk = fmaf(g, il, LOG2E * g_blog[bc*K_ + tid]);
      s_A[tid] = g_pts[bc*K_ + tid];
    }
    float hm = Hk;
    for (int off = 32; off; off >>= 1) hm = fmaxf(hm, __shfl_xor(hm, off));
    if ((tid & 63) == 0) s_w[tid >> 6] = hm;
    __syncthreads();
    const float Hbar = fmaxf(fmaxf(s_w[0], s_w[1]), fmaxf(s_w[2], s_w[3]));
    if (tid < K_) { float dh = Hk - Hbar; s_C[tid] = fexp2(dh); s_D[tid] = dh; }
    float4 Pn = g_P[b*N_ + n];
    __syncthreads();
    float S = 0.f, T = 0.f, M = -INFINITY;
#pragma unroll 4
    for (int k2 = 0; k2 < K_; k2 += 2) {
      float4 p1 = s_A[k2];
      float d1 = fmaf(Pn.x, p1.x, fmaf(Pn.y, p1.y, Pn.z * p1.z));
      float C1 = fmaxf((Pn.w + p1.w) - d1, 0.f);
      float w1 = C1 * nil;
      S = fmaf(s_C[k2], fexp2(w1), S);
      M = fmaxf(M, w1 + s_D[k2]);
      float4 p2 = s_A[k2+1];
      float d2 = fmaf(Pn.x, p2.x, fmaf(Pn.y, p2.y, Pn.z * p2.z));
      float C2 = fmaxf((Pn.w + p2.w) - d2, 0.f);
      float w2 = C2 * nil;
      T = fmaf(s_C[k2+1], fexp2(w2), T);
      M = fmaxf(M, w2 + s_D[k2+1]);
    }
    S += T;
    float lse = (S > 0.f) ? flog2(S) : M;
    float ft = -eps * LN2 * (Hbar + lse);
    if (mode == 0) {
      g_fbuf[src ^ 1][bc*N_ + n] = 0.5f * (g_fbuf[src][bc*N_ + n] + ft);
    } else {
      float a = y[(size_t)(b*N_ + n) * 6 + 3 + c];
      float acc = a * ft;
      for (int off = 32; off; off >>= 1) acc += __shfl_down(acc, off);
      __syncthreads();
      if ((tid & 63) == 0) s_w[tid >> 6] = acc;
      __syncthreads();
      if (tid == 0) g_S1a[blk2] = s_w[0] + s_w[1] + s_w[2] + s_w[3];
    }
  } else {
    // ---- yy ----
    float4* s_A = (float4*)s_M;
    float*  s_C = s_M + 512;
    float*  s_D = s_M + 640;
    const int bc = blk - (GTB + FTB);
    const int k = tid & (K_ - 1);
    if (tid < K_) {
      s_A[tid] = g_pts[bc*K_ + tid];
      float g = g_ybuf[src][bc*K_ + tid];
      s_C[tid] = fmaf(g, il, LOG2E * g_blog[bc*K_ + tid]);
      s_D[tid] = g;
    }
    __syncthreads();
    float4 Pk = s_A[k];
    float M = -INFINITY, S = 0.f;
    for (int m = 0; m < K_; ++m) {
      float4 pm = s_A[m];
      float d = fmaf(Pk.x, pm.x, fmaf(Pk.y, pm.y, Pk.z * pm.z));
      float C = fmaxf((Pk.w + pm.w) - d, 0.f);
      lse_up(fmaf(C, nil, s_C[m]), M, S);
    }
    float sv = -eps * LN2 * (M + flog2(S));
    if (mode == 0) {
      if (tid < K_) g_ybuf[src ^ 1][bc*K_ + k] = 0.5f * (s_D[k] + sv);
    } else {
      float val = (tid < K_) ? g_bval[bc*K_ + k] * sv : 0.f;
      for (int off = 32; off; off >>= 1) val += __shfl_down(val, off);
      __syncthreads();
      if ((tid & 63) == 0) s_w[tid >> 6] = val;
      __syncthreads();
      if (tid == 0) g_S2[bc] = s_w[0] + s_w[1] + s_w[2] + s_w[3];
    }
  }
}

// ============ finalize: F_a rows (combine of pass-12 partials) + a*F_a partial sums ============
__global__ __launch_bounds__(256) void k_finalize(const float* __restrict__ y) {
  const int tid = threadIdx.x;
  const int idx = blockIdx.x * 256 + tid;
  const int c  = idx >> 13;
  const int bn = idx & (B_*N_ - 1);
  const int b = bn >> 12, n = bn & (N_ - 1);
  __shared__ float s_scale[SC];
  __shared__ float s_mm;
  __shared__ float s_w[4];
  if (tid < SC) s_scale[tid] = g_Ubar[0][(b*SC + tid)*CH + c];
  __syncthreads();
  if (tid == 0) {
    float mm = s_scale[0];
#pragma unroll
    for (int s = 1; s < SC; ++s) mm = fmaxf(mm, s_scale[s]);
    s_mm = mm;
  }
  __syncthreads();
  const float Mmax = s_mm;
  if (tid < SC) s_scale[tid] = fexp2(s_scale[tid] - Mmax);
  __syncthreads();
  float S = 0.f;
#pragma unroll
  for (int s = 0; s < SC; ++s)
    S = fmaf(g_partS[0][(s*CH + c)*(B_*N_) + bn], s_scale[s], S);
  float sm = -EPS_LAST * LN2 * (Mmax + flog2(S));   // F_a
  float a = y[(size_t)(b*N_ + n)*6 + 3 + c];
  float acc = a * sm;
  for (int off = 32; off; off >>= 1) acc += __shfl_down(acc, off);
  if ((tid & 63) == 0) s_w[tid >> 6] = acc;
  __syncthreads();
  if (tid == 0) g_S3[blockIdx.x] = s_w[0] + s_w[1] + s_w[2] + s_w[3];
}

// ============ total ============
__global__ __launch_bounds__(1024) void k_total(float* __restrict__ out) {
  const int tid = threadIdx.x;
  float local = 0.f;
  if (tid < 768) local += g_Gab[tid];
  if (tid < FTB) local += g_S1a[tid];
  if (tid < 96)  local -= g_S3[tid];
  if (tid < 6)   local -= g_S2[tid];
  for (int off = 32; off; off >>= 1) local += __shfl_down(local, off);
  __shared__ float s_red[16];
  if ((tid & 63) == 0) s_red[tid >> 6] = local;
  __syncthreads();
  if (tid == 0) {
    float t = 0.f;
#pragma unroll
    for (int i = 0; i < 16; ++i) t += s_red[i];
    out[0] = t;
  }
}

extern "C" void kernel_launch(void* const* d_in, const int* in_sizes, int n_in,
                              void* d_out, int out_size, void* d_ws, size_t ws_size,
                              hipStream_t stream) {
  const float* y_hat = (const float*)d_in[0];
  const float* y     = (const float*)d_in[1];
  const float* vox   = (const float*)d_in[2];
  float* out = (float*)d_out;

  static const float eps_list[NEPS + 1] = {4.0f, 1.0f, 0.25f, 0.0625f, 0.015625f, 0.00390625f,
                                           0.0025f, 0.0025f, 0.0025f, 0.0025f, 0.0025f, 0.0025f,
                                           EPS_LAST};

  k_prep<<<8, 1024, 0, stream>>>(y);
  k_topk<<<6, 1024, 0, stream>>>(y_hat, vox);
  for (int it = 0; it <= NEPS; ++it) {
    float eps_prev = (it > 0) ? eps_list[it - 1] : 1.0f;
    int mode = (it == NEPS) ? 1 : 0;
    k_pass<<<NBLK, 256, 0, stream>>>(eps_list[it], eps_prev, it, mode, y);
  }
  k_finalize<<<96, 256, 0, stream>>>(y);
  k_total<<<1, 1024, 0, stream>>>(out);
}

// Round 17
// 250.378 us; speedup vs baseline: 16.4731x; 1.1260x over previous
//
#include <hip/hip_runtime.h>
#include <math.h>

#define B_   2
#define N_   4096
#define V_   32768
#define K_   128
#define SC   16              // m-tiles of 256
#define CH   3
#define NEPS 12
#define XXB  256             // B * 8 n-chunks(512) * 16 m-tiles
#define FTB  96
#define GTB  192
#define YYB  6
#define NBLK (XXB + FTB + GTB + YYB)   // 550
#define TCAP 2048

#define LOG2E 1.4426950408889634f
#define LN2   0.6931471805599453f
#define EPS_LAST 0.0025f

typedef float f2 __attribute__((ext_vector_type(2)));

// raw hardware transcendentals (skip OCML subnormal-fixup wrappers)
__device__ __forceinline__ float fexp2(float x) {
  float r; asm("v_exp_f32 %0, %1" : "=v"(r) : "v"(x)); return r;
}
__device__ __forceinline__ float flog2(float x) {
  float r; asm("v_log_f32 %0, %1" : "=v"(r) : "v"(x)); return r;
}

// ---- static device scratch (ping-pong where cross-pass) ----
__device__ float4 g_P   [B_*N_];
__device__ float  g_alog[B_*CH*N_];
__device__ float  g_fa  [2][B_*CH*N_];
__device__ float  g_partS[2][SC*CH*B_*N_];
__device__ float  g_Ubar[2][B_*SC*CH];
__device__ float4 g_pts [B_*CH*K_];
__device__ float  g_blog[B_*CH*K_];
__device__ float  g_bval[B_*CH*K_];
__device__ float  g_fbuf[2][B_*CH*N_];
__device__ float  g_gbuf[2][B_*CH*K_];
__device__ float  g_ybuf[2][B_*CH*K_];
__device__ float  g_S1a[FTB];
__device__ float  g_Gab[768];
__device__ float  g_S2[6];
__device__ float  g_S3[96];

__device__ __forceinline__ void lse_up(float t, float& m, float& s) {
  float mn = fmaxf(m, t);
  float e  = fexp2(-fabsf(t - m));
  bool  gt = t > m;
  float mulv = gt ? e : 1.0f;
  float addv = gt ? 1.0f : e;
  s = fmaf(s, mulv, addv);
  m = mn;
}
__device__ __forceinline__ void lse_merge(float& M, float& S, float oM, float oS) {
  float mn = fmaxf(M, oM);
  float e  = fexp2(-fabsf(M - oM));
  bool  gt = oM > M;
  float sm = gt ? e : 1.0f;
  float so = gt ? 1.0f : e;
  S = fmaf(S, sm, oS * so);
  M = mn;
}

// ============ prep ============
__global__ __launch_bounds__(1024) void k_prep(const float* __restrict__ y) {
  const int bn = blockIdx.x * 1024 + threadIdx.x;
  const int b = bn >> 12, n = bn & (N_ - 1);
  const float* yr = y + (size_t)bn * 6;
  float x0 = yr[0], x1 = yr[1], x2 = yr[2];
  g_P[bn] = make_float4(x0, x1, x2, 0.5f * (x0*x0 + x1*x1 + x2*x2));
#pragma unroll
  for (int c = 0; c < CH; ++c) {
    float w  = yr[3 + c];
    float al = flog2(fmaxf(w, 1e-20f)) * LN2;
    const int o = (b*CH + c)*N_ + n;
    g_alog[o] = al; g_fa[0][o] = 0.f; g_fbuf[0][o] = 0.f;
  }
}

// ============ fused top-k: one block per (b,c) row, LDS histogram select ============
__global__ __launch_bounds__(1024) void k_topk(const float* __restrict__ yhat,
                                               const float* __restrict__ vox) {
  const int bc = blockIdx.x, tid = threadIdx.x;
  __shared__ int   s_hist[8192];
  __shared__ int   s_suf[1024];
  __shared__ float s_tv[TCAP];
  __shared__ int   s_ti[TCAP];
  __shared__ float s_wv[K_];
  __shared__ int   s_wi[K_];
  __shared__ int   s_wtot[16];
  __shared__ int   s_pos, s_eq, s_bs, s_c1, s_cnt;

  if (tid < K_) { g_gbuf[0][bc*K_ + tid] = 0.f; g_ybuf[0][bc*K_ + tid] = 0.f; }
#pragma unroll
  for (int j = 0; j < 8; ++j) s_hist[tid + j*1024] = 0;
  if (tid == 0) { s_pos = 0; s_eq = 0; }

  const float* row = yhat + (size_t)bc * V_;
  float v[32];
#pragma unroll
  for (int j = 0; j < 32; ++j) v[j] = row[tid + j * 1024];
  __syncthreads();
#pragma unroll
  for (int j = 0; j < 32; ++j) {
    unsigned b = __float_as_uint(v[j]);
    unsigned bk = (b >> 31) ? 0u : min(b >> 17, 8191u);
    atomicAdd(&s_hist[bk], 1);
  }
  __syncthreads();
  const int base = tid * 8;
  int cs = 0;
#pragma unroll
  for (int i = 0; i < 8; ++i) cs += s_hist[base + i];
  s_suf[tid] = cs;
  __syncthreads();
  for (int off = 1; off < 1024; off <<= 1) {
    int vv = s_suf[tid];
    int add = (tid + off < 1024) ? s_suf[tid + off] : 0;
    __syncthreads();
    s_suf[tid] = vv + add;
    __syncthreads();
  }
  int nxt = (tid < 1023) ? s_suf[tid + 1] : 0;
  if (s_suf[tid] >= K_ && nxt < K_) {
    int cnt = nxt, bstar = base, c1 = nxt;
    for (int b2 = base + 7; b2 >= base; --b2) {
      int h = s_hist[b2];
      if (cnt + h >= K_) { bstar = b2; c1 = cnt; break; }
      cnt += h;
    }
    s_bs = bstar; s_c1 = c1;
  }
  __syncthreads();
  const int bstar = s_bs, c1 = s_c1;
#pragma unroll
  for (int j = 0; j < 32; ++j) {
    unsigned b = __float_as_uint(v[j]);
    int bk = (b >> 31) ? 0 : (int)min(b >> 17, 8191u);
    int i = tid + j * 1024;
    if (bk > bstar) {
      int p = atomicAdd(&s_pos, 1);
      s_wv[p] = v[j]; s_wi[p] = i;
    } else if (bk == bstar) {
      int p = atomicAdd(&s_eq, 1);
      if (p < TCAP) { s_tv[p] = v[j]; s_ti[p] = i; }
    }
  }
  __syncthreads();
  const int tcnt = s_eq;
  if (tcnt <= TCAP) {
    const int need = K_ - c1;
    for (int e = tid; e < tcnt; e += 1024) {
      float vv = s_tv[e]; int i = s_ti[e];
      int rank = 0;
      for (int j2 = 0; j2 < tcnt; ++j2) {
        float ov = s_tv[j2]; int oi = s_ti[j2];
        rank += (ov > vv || (ov == vv && oi < i)) ? 1 : 0;
      }
      if (rank < need) { s_wv[c1 + rank] = vv; s_wi[c1 + rank] = i; }
    }
    __syncthreads();
  } else {
    unsigned lo = 0u, hi = 0x7f800000u;
    while (lo < hi) {
      unsigned mid = lo + ((hi - lo + 1u) >> 1);
      if (tid == 0) s_cnt = 0;
      __syncthreads();
      int local = 0;
#pragma unroll
      for (int j = 0; j < 32; ++j) local += (__float_as_uint(v[j]) >= mid) ? 1 : 0;
      for (int off = 32; off; off >>= 1) local += __shfl_down(local, off);
      if ((tid & 63) == 0 && local) atomicAdd(&s_cnt, local);
      __syncthreads();
      int cnt = s_cnt;
      __syncthreads();
      if (cnt >= K_) lo = mid; else hi = mid - 1u;
    }
    const unsigned T = lo;
    if (tid == 0) s_cnt = 0;
    __syncthreads();
#pragma unroll
    for (int j = 0; j < 32; ++j) {
      if (__float_as_uint(v[j]) > T) {
        int p = atomicAdd(&s_cnt, 1);
        s_wv[p] = v[j]; s_wi[p] = tid + j * 1024;
      }
    }
    __syncthreads();
    int got = s_cnt;
    __syncthreads();
    for (int chunk = 0; chunk < 32 && got < K_; ++chunk) {
      int i = chunk * 1024 + tid;
      bool f = (__float_as_uint(v[chunk]) == T);
      unsigned long long mask = __ballot(f);
      int lane = tid & 63, wv = tid >> 6;
      int wpre = __popcll(mask & ((1ULL << lane) - 1ULL));
      if (lane == 0) s_wtot[wv] = __popcll(mask);
      __syncthreads();
      int pre = wpre, tot = 0;
      for (int w = 0; w < 16; ++w) { if (w < wv) pre += s_wtot[w]; tot += s_wtot[w]; }
      if (f && got + pre < K_) { s_wv[got + pre] = v[chunk]; s_wi[got + pre] = i; }
      got = min(got + tot, K_);
      __syncthreads();
    }
  }
  if (tid < K_) {
    float mv = s_wv[tid]; int mi = s_wi[tid];
    float p0 = vox[(size_t)mi*3+0], p1 = vox[(size_t)mi*3+1], p2 = vox[(size_t)mi*3+2];
    g_pts [bc*K_ + tid] = make_float4(p0, p1, p2, 0.5f*(p0*p0 + p1*p1 + p2*p2));
    g_bval[bc*K_ + tid] = mv;
    g_blog[bc*K_ + tid] = flog2(fmaxf(mv, 1e-20f)) * LN2;
  }
}

// ============ fused pass: xx(256, w/ inline combine) + ab-ft(96) + ab-gt(192) + yy(6) ============
__global__ __launch_bounds__(256) void k_pass(float eps, float eps_prev, int it, int mode,
                                              const float* __restrict__ y) {
  const float il = LOG2E / eps, nil = -il;
  const int blk = blockIdx.x, tid = threadIdx.x;
  const int src = it & 1;
  __shared__ float s_M[2048];     // 128 records x 16 floats (xx) / aliased by ft,yy
  __shared__ float s_scale[48];
  __shared__ float s_Mx[3];
  __shared__ float s_w[12];

  if (blk < XXB) {
    // ---- xx block (b, I, J): inline combine for m-tile J, then 512n x 256m loop ----
    const int J = blk & 15;
    const int I = (blk >> 4) & 7;
    const int b = blk >> 7;
    const int r  = (J << 8) + tid;          // this thread's m-row
    const int bn_r = b*N_ + r;
    float U[CH];
    if (it == 0) {
#pragma unroll
      for (int c = 0; c < CH; ++c) U[c] = LOG2E * g_alog[(b*CH + c)*N_ + r];
    } else {
      const int pv = src ^ 1;
      if (tid < 48) {
        int c = tid >> 4, Jp = tid & 15;
        s_scale[tid] = g_Ubar[pv][(b*SC + Jp)*CH + c];
      }
      __syncthreads();
      if (tid < 3) {
        float mm = s_scale[tid*16];
#pragma unroll
        for (int j = 1; j < 16; ++j) mm = fmaxf(mm, s_scale[tid*16 + j]);
        s_Mx[tid] = mm;
      }
      __syncthreads();
      if (tid < 48) s_scale[tid] = fexp2(s_scale[tid] - s_Mx[tid >> 4]);
      __syncthreads();
#pragma unroll
      for (int c = 0; c < CH; ++c) {
        float S = 0.f;
#pragma unroll
        for (int Jp = 0; Jp < 16; ++Jp)
          S = fmaf(g_partS[pv][(Jp*CH + c)*(B_*N_) + bn_r], s_scale[c*16 + Jp], S);
        float sm = -eps_prev * LN2 * (s_Mx[c] + flog2(S));
        const int o = (b*CH + c)*N_ + r;
        float fn = 0.5f * (g_fa[src ^ 1][o] + sm);
        g_fa[src][o] = fn;
        U[c] = fmaf(fn, il, LOG2E * g_alog[o]);
      }
      __syncthreads();                       // s_scale/s_Mx done before reuse of LDS
    }
    // tile max of U per channel
    float Ub[CH];
#pragma unroll
    for (int c = 0; c < CH; ++c) {
      float u = U[c];
      for (int off = 32; off; off >>= 1) u = fmaxf(u, __shfl_xor(u, off));
      if ((tid & 63) == 0) s_w[(tid >> 6)*3 + c] = u;
    }
    __syncthreads();
#pragma unroll
    for (int c = 0; c < CH; ++c)
      Ub[c] = fmaxf(fmaxf(s_w[c], s_w[3 + c]), fmaxf(s_w[6 + c], s_w[9 + c]));
    if (tid < 3) g_Ubar[src][(b*SC + J)*CH + tid] = Ub[tid];
    // build prescaled record tile in LDS
    {
      float4 Pm = g_P[bn_r];
      const int pp = tid >> 1, par = tid & 1;
      float* rec = s_M + pp*16;
      rec[0 + par] = il * Pm.x;
      rec[2 + par] = il * Pm.y;
      rec[4 + par] = il * Pm.z;
      rec[6 + par] = -il * Pm.w;
#pragma unroll
      for (int c = 0; c < CH; ++c) rec[8 + 2*c + par] = fexp2(U[c] - Ub[c]);
    }
    __syncthreads();
    // n loop: 2 n per thread
    const int bn0 = b*N_ + (I << 9) + tid;
    const int bn1 = bn0 + 256;
    const float4 Pn0 = g_P[bn0], Pn1 = g_P[bn1];
    const float xs0 = Pn0.x, ys0 = Pn0.y, zs0 = Pn0.z, nn0 = nil * Pn0.w;
    const float xs1 = Pn1.x, ys1 = Pn1.y, zs1 = Pn1.z, nn1 = nil * Pn1.w;
    const f2 zz = {0.f, 0.f};
    f2 a00 = zz, a01 = zz, a02 = zz, a10 = zz, a11 = zz, a12 = zz;
    for (int j = 0; j < 128; ++j) {
      const float* Mj = s_M + j*16;
      const float4 q0 = *(const float4*)(Mj);
      const float4 q1 = *(const float4*)(Mj + 4);
      const float4 q2 = *(const float4*)(Mj + 8);
      const float2 q3 = *(const float2*)(Mj + 12);
      f2 t0 = f2{q1.z, q1.w} + nn0;
      t0 = f2{q1.x, q1.y} * zs0 + t0;
      t0 = f2{q0.z, q0.w} * ys0 + t0;
      t0 = f2{q0.x, q0.y} * xs0 + t0;
      t0 = __builtin_elementwise_min(t0, zz);
      f2 e0; e0.x = fexp2(t0.x); e0.y = fexp2(t0.y);
      a00 = f2{q2.x, q2.y} * e0 + a00;
      a01 = f2{q2.z, q2.w} * e0 + a01;
      a02 = f2{q3.x, q3.y} * e0 + a02;
      f2 t1 = f2{q1.z, q1.w} + nn1;
      t1 = f2{q1.x, q1.y} * zs1 + t1;
      t1 = f2{q0.z, q0.w} * ys1 + t1;
      t1 = f2{q0.x, q0.y} * xs1 + t1;
      t1 = __builtin_elementwise_min(t1, zz);
      f2 e1; e1.x = fexp2(t1.x); e1.y = fexp2(t1.y);
      a10 = f2{q2.x, q2.y} * e1 + a10;
      a11 = f2{q2.z, q2.w} * e1 + a11;
      a12 = f2{q3.x, q3.y} * e1 + a12;
    }
    float* pc = g_partS[src];
    pc[(J*CH + 0)*(B_*N_) + bn0] = a00.x + a00.y;
    pc[(J*CH + 1)*(B_*N_) + bn0] = a01.x + a01.y;
    pc[(J*CH + 2)*(B_*N_) + bn0] = a02.x + a02.y;
    pc[(J*CH + 0)*(B_*N_) + bn1] = a10.x + a10.y;
    pc[(J*CH + 1)*(B_*N_) + bn1] = a11.x + a11.y;
    pc[(J*CH + 2)*(B_*N_) + bn1] = a12.x + a12.y;
  } else if (blk < XXB + FTB) {
    // ---- ab ft ----
    float4* s_A = (float4*)s_M;           // [128]
    float*  s_C = s_M + 512;
    float*  s_D = s_M + 640;
    const int blk2 = blk - XXB;
    const int bc = blk2 >> 4;
    const int b = bc / 3, c = bc % 3;
    const int n = ((blk2 & 15) << 8) + tid;
    float Hk = -INFINITY;
    if (tid < K_) {
      float g = g_gbuf[src][bc*K_ + tid];
      Hk = fmaf(g, il, LOG2E * g_blog[bc*K_ + tid]);
      s_A[tid] = g_pts[bc*K_ + tid];
    }
    float hm = Hk;
    for (int off = 32; off; off >>= 1) hm = fmaxf(hm, __shfl_xor(hm, off));
    if ((tid & 63) == 0) s_w[tid >> 6] = hm;
    __syncthreads();
    const float Hbar = fmaxf(fmaxf(s_w[0], s_w[1]), fmaxf(s_w[2], s_w[3]));
    if (tid < K_) { float dh = Hk - Hbar; s_C[tid] = fexp2(dh); s_D[tid] = dh; }
    float4 Pn = g_P[b*N_ + n];
    __syncthreads();
    float S = 0.f, T = 0.f, M = -INFINITY;
#pragma unroll 4
    for (int k2 = 0; k2 < K_; k2 += 2) {
      float4 p1 = s_A[k2];
      float d1 = fmaf(Pn.x, p1.x, fmaf(Pn.y, p1.y, Pn.z * p1.z));
      float C1 = fmaxf((Pn.w + p1.w) - d1, 0.f);
      float w1 = C1 * nil;
      S = fmaf(s_C[k2], fexp2(w1), S);
      M = fmaxf(M, w1 + s_D[k2]);
      float4 p2 = s_A[k2+1];
      float d2 = fmaf(Pn.x, p2.x, fmaf(Pn.y, p2.y, Pn.z * p2.z));
      float C2 = fmaxf((Pn.w + p2.w) - d2, 0.f);
      float w2 = C2 * nil;
      T = fmaf(s_C[k2+1], fexp2(w2), T);
      M = fmaxf(M, w2 + s_D[k2+1]);
    }
    S += T;
    float lse = (S > 0.f) ? flog2(S) : M;
    float ft = -eps * LN2 * (Hbar + lse);
    if (mode == 0) {
      g_fbuf[src ^ 1][bc*N_ + n] = 0.5f * (g_fbuf[src][bc*N_ + n] + ft);
    } else {
      float a = y[(size_t)(b*N_ + n) * 6 + 3 + c];
      float acc = a * ft;
      for (int off = 32; off; off >>= 1) acc += __shfl_down(acc, off);
      __syncthreads();
      if ((tid & 63) == 0) s_w[tid >> 6] = acc;
      __syncthreads();
      if (tid == 0) g_S1a[blk2] = s_w[0] + s_w[1] + s_w[2] + s_w[3];
    }
  } else if (blk < XXB + FTB + GTB) {
    // ---- ab gt: one wave per (bc,k), 4 LSE chains ----
    const int job = (blk - (XXB + FTB)) * 4 + (tid >> 6);
    const int bc = job >> 7, k = job & (K_ - 1);
    const int b = bc / 3;
    const int lane = tid & 63;
    float4 Pk = g_pts[bc*K_ + k];
    float M0=-INFINITY,S0=0.f,M1=-INFINITY,S1=0.f,M2=-INFINITY,S2=0.f,M3=-INFINITY,S3=0.f;
    for (int j = 0; j < 64; j += 4) {
#pragma unroll
      for (int u = 0; u < 4; ++u) {
        int n = ((j + u) << 6) + lane;
        float4 pm = g_P[b*N_ + n];
        float Hn = fmaf(g_fbuf[src][bc*N_ + n], il, LOG2E * g_alog[bc*N_ + n]);
        float d = fmaf(Pk.x, pm.x, fmaf(Pk.y, pm.y, Pk.z * pm.z));
        float C = fmaxf((Pk.w + pm.w) - d, 0.f);
        float t = fmaf(C, nil, Hn);
        if (u == 0) lse_up(t, M0, S0);
        else if (u == 1) lse_up(t, M1, S1);
        else if (u == 2) lse_up(t, M2, S2);
        else lse_up(t, M3, S3);
      }
    }
    lse_merge(M0, S0, M1, S1);
    lse_merge(M2, S2, M3, S3);
    lse_merge(M0, S0, M2, S2);
    for (int off = 1; off < 64; off <<= 1) {
      float oM = __shfl_xor(M0, off);
      float oS = __shfl_xor(S0, off);
      lse_merge(M0, S0, oM, oS);
    }
    if (lane == 0) {
      float gt = -eps * LN2 * (M0 + flog2(S0));
      const int o = bc*K_ + k;
      if (mode == 0) g_gbuf[src ^ 1][o] = 0.5f * (g_gbuf[src][o] + gt);
      else           g_Gab[job] = g_bval[o] * gt;
    }
  } else {
    // ---- yy ----
    float4* s_A = (float4*)s_M;
    float*  s_C = s_M + 512;
    float*  s_D = s_M + 640;
    const int bc = blk - (XXB + FTB + GTB);
    const int k = tid & (K_ - 1);
    if (tid < K_) {
      s_A[tid] = g_pts[bc*K_ + tid];
      float g = g_ybuf[src][bc*K_ + tid];
      s_C[tid] = fmaf(g, il, LOG2E * g_blog[bc*K_ + tid]);
      s_D[tid] = g;
    }
    __syncthreads();
    float4 Pk = s_A[k];
    float M = -INFINITY, S = 0.f;
    for (int m = 0; m < K_; ++m) {
      float4 pm = s_A[m];
      float d = fmaf(Pk.x, pm.x, fmaf(Pk.y, pm.y, Pk.z * pm.z));
      float C = fmaxf((Pk.w + pm.w) - d, 0.f);
      lse_up(fmaf(C, nil, s_C[m]), M, S);
    }
    float sv = -eps * LN2 * (M + flog2(S));
    if (mode == 0) {
      if (tid < K_) g_ybuf[src ^ 1][bc*K_ + k] = 0.5f * (s_D[k] + sv);
    } else {
      float val = (tid < K_) ? g_bval[bc*K_ + k] * sv : 0.f;
      for (int off = 32; off; off >>= 1) val += __shfl_down(val, off);
      __syncthreads();
      if ((tid & 63) == 0) s_w[tid >> 6] = val;
      __syncthreads();
      if (tid == 0) g_S2[bc] = s_w[0] + s_w[1] + s_w[2] + s_w[3];
    }
  }
}

// ============ finalize: F_a rows (combine of pass-12 partials) + a*F_a partial sums ============
__global__ __launch_bounds__(256) void k_finalize(const float* __restrict__ y) {
  const int tid = threadIdx.x;
  const int idx = blockIdx.x * 256 + tid;
  const int c  = idx >> 13;
  const int bn = idx & (B_*N_ - 1);
  const int b = bn >> 12, n = bn & (N_ - 1);
  __shared__ float s_scale[SC];
  __shared__ float s_mm;
  __shared__ float s_w[4];
  if (tid < SC) s_scale[tid] = g_Ubar[0][(b*SC + tid)*CH + c];
  __syncthreads();
  if (tid == 0) {
    float mm = s_scale[0];
#pragma unroll
    for (int s = 1; s < SC; ++s) mm = fmaxf(mm, s_scale[s]);
    s_mm = mm;
  }
  __syncthreads();
  const float Mmax = s_mm;
  if (tid < SC) s_scale[tid] = fexp2(s_scale[tid] - Mmax);
  __syncthreads();
  float S = 0.f;
#pragma unroll
  for (int s = 0; s < SC; ++s)
    S = fmaf(g_partS[0][(s*CH + c)*(B_*N_) + bn], s_scale[s], S);
  float sm = -EPS_LAST * LN2 * (Mmax + flog2(S));   // F_a
  float a = y[(size_t)(b*N_ + n)*6 + 3 + c];
  float acc = a * sm;
  for (int off = 32; off; off >>= 1) acc += __shfl_down(acc, off);
  if ((tid & 63) == 0) s_w[tid >> 6] = acc;
  __syncthreads();
  if (tid == 0) g_S3[blockIdx.x] = s_w[0] + s_w[1] + s_w[2] + s_w[3];
}

// ============ total ============
__global__ __launch_bounds__(1024) void k_total(float* __restrict__ out) {
  const int tid = threadIdx.x;
  float local = 0.f;
  if (tid < 768) local += g_Gab[tid];
  if (tid < FTB) local += g_S1a[tid];
  if (tid < 96)  local -= g_S3[tid];
  if (tid < 6)   local -= g_S2[tid];
  for (int off = 32; off; off >>= 1) local += __shfl_down(local, off);
  __shared__ float s_red[16];
  if ((tid & 63) == 0) s_red[tid >> 6] = local;
  __syncthreads();
  if (tid == 0) {
    float t = 0.f;
#pragma unroll
    for (int i = 0; i < 16; ++i) t += s_red[i];
    out[0] = t;
  }
}

extern "C" void kernel_launch(void* const* d_in, const int* in_sizes, int n_in,
                              void* d_out, int out_size, void* d_ws, size_t ws_size,
                              hipStream_t stream) {
  const float* y_hat = (const float*)d_in[0];
  const float* y     = (const float*)d_in[1];
  const float* vox   = (const float*)d_in[2];
  float* out = (float*)d_out;

  static const float eps_list[NEPS + 1] = {4.0f, 1.0f, 0.25f, 0.0625f, 0.015625f, 0.00390625f,
                                           0.0025f, 0.0025f, 0.0025f, 0.0025f, 0.0025f, 0.0025f,
                                           EPS_LAST};

  k_prep<<<8, 1024, 0, stream>>>(y);
  k_topk<<<6, 1024, 0, stream>>>(y_hat, vox);
  for (int it = 0; it <= NEPS; ++it) {
    float eps_prev = (it > 0) ? eps_list[it - 1] : 1.0f;
    int mode = (it == NEPS) ? 1 : 0;
    k_pass<<<NBLK, 256, 0, stream>>>(eps_list[it], eps_prev, it, mode, y);
  }
  k_finalize<<<96, 256, 0, stream>>>(y);
  k_total<<<1, 1024, 0, stream>>>(out);
}